// Round 9
// baseline (325.591 us; speedup 1.0000x reference)
//
#include <hip/hip_runtime.h>

#define NN 50000
#define NP 50048   // rows padded to multiple of 128
#define NE 800000
#define D 128
#define UNITS 256
#define KTOT 512
#define SCAN_NB 50   // 50 blocks x 1024 elements covers 50000
#define NREP 16
#define CONV_NB 6250 // NN*D/4/256

typedef __attribute__((ext_vector_type(8))) short short8;
typedef __attribute__((ext_vector_type(4))) float floatx4;

__device__ inline unsigned short f2b(float f) {          // fp32 -> bf16 RNE
    unsigned u = __float_as_uint(f);
    return (unsigned short)((u + 0x7fff + ((u >> 16) & 1)) >> 16);
}
__device__ inline float2 bx2f(unsigned v) {              // packed bf16x2 -> float2
    float2 r;
    r.x = __uint_as_float(v << 16);
    r.y = __uint_as_float(v & 0xffff0000u);
    return r;
}

// ---------- count: 16 replicated histograms + per-edge rank ----------
__global__ void count_kernel(const int* __restrict__ row, int* __restrict__ cnt16,
                             int* __restrict__ rank, int E) {
    int e = blockIdx.x * blockDim.x + threadIdx.x;
    if (e < E) {
        int rep = (e >> 6) & (NREP - 1);        // whole wave -> same replica
        rank[e] = atomicAdd(&cnt16[rep * NN + row[e]], 1);
    }
}

// ---------- 3-phase exclusive scan; also prefixes the 16 replicas per node ----------
__global__ __launch_bounds__(256) void scanA_kernel(int* __restrict__ cnt16,
                                                    int* __restrict__ row_ptr,
                                                    int* __restrict__ bsum) {
    __shared__ int s[256];
    int b = blockIdx.x, t = threadIdx.x;
    int base = b * 1024 + t * 4;
    int v[4];
    int sum = 0;
#pragma unroll
    for (int i = 0; i < 4; ++i) {
        int idx = base + i;
        int tot = 0;
        if (idx < NN) {
            int c[NREP];
            int run = 0;
#pragma unroll
            for (int r = 0; r < NREP; ++r) c[r] = cnt16[r * NN + idx];
#pragma unroll
            for (int r = 0; r < NREP; ++r) {
                cnt16[r * NN + idx] = run;
                run += c[r];
            }
            tot = run;
        }
        v[i] = tot;
        sum += tot;
    }
    s[t] = sum;
    __syncthreads();
    for (int off = 1; off < 256; off <<= 1) {
        int add = (t >= off) ? s[t - off] : 0;
        __syncthreads();
        s[t] += add;
        __syncthreads();
    }
    int run = s[t] - sum;
#pragma unroll
    for (int i = 0; i < 4; ++i) {
        int idx = base + i;
        if (idx < NN) row_ptr[idx] = run;
        run += v[i];
    }
    if (t == 255) bsum[b] = s[255];
}

__global__ void scanB_kernel(int* __restrict__ bsum, int* __restrict__ row_ptr) {
    if (threadIdx.x == 0 && blockIdx.x == 0) {
        int run = 0;
        for (int i = 0; i < SCAN_NB; ++i) {
            int v = bsum[i];
            bsum[i] = run;
            run += v;
        }
        row_ptr[NN] = run;
    }
}

__global__ __launch_bounds__(256) void scanC_kernel(int* __restrict__ row_ptr,
                                                    const int* __restrict__ bsum) {
    int b = blockIdx.x, t = threadIdx.x;
    int off = bsum[b];
    int base = b * 1024 + t * 4;
#pragma unroll
    for (int i = 0; i < 4; ++i) {
        int idx = base + i;
        if (idx < NN) row_ptr[idx] += off;
    }
}

// ---------- CSR fill (no atomics): (col, raw weight) records ----------
__global__ void fill_kernel(const int* __restrict__ row, const int* __restrict__ col,
                            const float* __restrict__ w, const int* __restrict__ rank,
                            const int* __restrict__ row_ptr, const int* __restrict__ cnt16,
                            int2* __restrict__ edges, int E) {
    int e = blockIdx.x * blockDim.x + threadIdx.x;
    if (e >= E) return;
    int r = row[e];
    int rep = (e >> 6) & (NREP - 1);
    int pos = row_ptr[r] + cnt16[rep * NN + r] + rank[e];
    edges[pos] = make_int2(col[e], __float_as_int(w[e]));
}

// ---------- per-node degree -> dis (wave per node, coalesced) ----------
__global__ __launch_bounds__(256) void degdis_kernel(const int* __restrict__ row_ptr,
                                                     const int2* __restrict__ edges,
                                                     float* __restrict__ dis) {
    int node = blockIdx.x * 4 + (threadIdx.x >> 6);
    int l = threadIdx.x & 63;
    if (node >= NN) return;
    int beg = row_ptr[node], end = row_ptr[node + 1];
    float s = 0.f;
    for (int e = beg + l; e < end; e += 64) s += __int_as_float(edges[e].y);
#pragma unroll
    for (int off = 32; off; off >>= 1) s += __shfl_down(s, off);
    if (l == 0) dis[node] = s > 0.f ? rsqrtf(s) : 0.f;
}

// ---------- prep: fp32->bf16 convert of x  +  W[512][256] -> Wt[256][512] bf16 ----------
__global__ __launch_bounds__(256) void prep_kernel(const float* __restrict__ x,
                                                   unsigned* __restrict__ xb,
                                                   const float* __restrict__ W,
                                                   short* __restrict__ Wt) {
    __shared__ float tile[32][33];
    if (blockIdx.x < CONV_NB) {
        int t = blockIdx.x * 256 + threadIdx.x;
        float4 v = ((const float4*)x)[t];
        uint2 o;
        o.x = (unsigned)f2b(v.x) | ((unsigned)f2b(v.y) << 16);
        o.y = (unsigned)f2b(v.z) | ((unsigned)f2b(v.w) << 16);
        ((uint2*)xb)[t] = o;
    } else {
        int b = blockIdx.x - CONV_NB;           // 0..127
        int kb = (b & 15) * 32;
        int nb = (b >> 4) * 32;
        int tx = threadIdx.x & 31, ty = threadIdx.x >> 5;
        for (int i = 0; i < 32; i += 8)
            tile[ty + i][tx] = W[(size_t)(kb + ty + i) * UNITS + nb + tx];
        __syncthreads();
        for (int i = 0; i < 32; i += 8)
            Wt[(size_t)(nb + ty + i) * KTOT + kb + tx] = (short)f2b(tile[tx][ty + i]);
    }
}

// ---------- propagation: 4 edges per wave-load; hop1 fuses weight normalization ----------
__device__ inline void acc8(float* acc, uint4 v, float w) {
    float2 f0 = bx2f(v.x), f1 = bx2f(v.y), f2 = bx2f(v.z), f3 = bx2f(v.w);
    acc[0] = fmaf(w, f0.x, acc[0]); acc[1] = fmaf(w, f0.y, acc[1]);
    acc[2] = fmaf(w, f1.x, acc[2]); acc[3] = fmaf(w, f1.y, acc[3]);
    acc[4] = fmaf(w, f2.x, acc[4]); acc[5] = fmaf(w, f2.y, acc[5]);
    acc[6] = fmaf(w, f3.x, acc[6]); acc[7] = fmaf(w, f3.y, acc[7]);
}

template <bool NORM>
__global__ __launch_bounds__(256) void gather_kernel(const unsigned* __restrict__ hprev,
                                                     unsigned* __restrict__ hnext,
                                                     const int* __restrict__ row_ptr,
                                                     int2* __restrict__ edges,
                                                     const float* __restrict__ dis) {
    int node = blockIdx.x * 4 + (threadIdx.x >> 6);
    if (node >= NN) return;
    int l = threadIdx.x & 63;
    int g = l >> 4;           // edge subgroup 0..3
    int s = l & 15;           // feature segment
    const uint4* hp4 = (const uint4*)hprev;   // one row = 16 uint4
    int beg = row_ptr[node], end = row_ptr[node + 1];
    float dr = NORM ? dis[node] : 1.f;

    float acc[8] = {0.f, 0.f, 0.f, 0.f, 0.f, 0.f, 0.f, 0.f};
    for (int e = beg; e < end; e += 8) {
        int i0 = e + g;
        int i1 = e + 4 + g;
        long long p0 = __builtin_nontemporal_load(
            (const long long*)&edges[i0 < end ? i0 : end - 1]);
        long long p1 = __builtin_nontemporal_load(
            (const long long*)&edges[i1 < end ? i1 : end - 1]);
        int c0 = (int)p0, c1 = (int)p1;
        float w0 = __int_as_float((int)(p0 >> 32));
        float w1 = __int_as_float((int)(p1 >> 32));
        if (NORM) {
            w0 *= dr * dis[c0];
            w1 *= dr * dis[c1];
        }
        w0 = (i0 < end) ? w0 : 0.f;
        w1 = (i1 < end) ? w1 : 0.f;
        uint4 v0 = hp4[(size_t)c0 * 16 + s];
        uint4 v1 = hp4[(size_t)c1 * 16 + s];
        acc8(acc, v0, w0);
        acc8(acc, v1, w1);
        if (NORM && s == 0) {                  // persist normalized weights for hops 2/3
            if (i0 < end) edges[i0].y = __float_as_int(w0);
            if (i1 < end) edges[i1].y = __float_as_int(w1);
        }
    }
    // butterfly over the 4 groups (lane bits 4,5)
#pragma unroll
    for (int i = 0; i < 8; ++i) {
        acc[i] += __shfl_xor(acc[i], 16);
        acc[i] += __shfl_xor(acc[i], 32);
    }
    if (g == 0) {
        uint4 sv = hp4[(size_t)node * 16 + s];   // self loop, weight 1
        acc8(acc, sv, 1.f);
        uint4 o;
        o.x = (unsigned)f2b(acc[0]) | ((unsigned)f2b(acc[1]) << 16);
        o.y = (unsigned)f2b(acc[2]) | ((unsigned)f2b(acc[3]) << 16);
        o.z = (unsigned)f2b(acc[4]) | ((unsigned)f2b(acc[5]) << 16);
        o.w = (unsigned)f2b(acc[6]) | ((unsigned)f2b(acc[7]) << 16);
        ((uint4*)hnext)[(size_t)node * 16 + s] = o;
    }
}

// ---------- MFMA GEMM: out[NP,256] = relu(bias + A[m][512] @ Wt^T) ----------
#define BK 64
#define GLDS(g, l)                                                                      \
    __builtin_amdgcn_global_load_lds((const __attribute__((address_space(1))) void*)(g), \
                                     (__attribute__((address_space(3))) void*)(l), 16, 0, 0)

__global__ __launch_bounds__(256) void gemm_mfma(const short* __restrict__ A0,
                                                 const short* __restrict__ Wt,
                                                 const float* __restrict__ bias,
                                                 float* __restrict__ C) {
    __shared__ short As[128 * BK];   // 16 KB, [m][k], chunk c stored at c^(row&7)
    __shared__ short Bs[128 * BK];   // 16 KB, [n][k]
    const int t = threadIdx.x;
    const int m0 = blockIdx.x * 128;
    const int n0 = blockIdx.y * 128;
    const int w = t >> 6;
    const int l = t & 63;
    const int wr = (w >> 1) * 64;
    const int wc = (w & 1) * 64;
    const int lm = l & 15;
    const int lg = l >> 4;                  // 0..3

    const int srow = l >> 3;                // 0..7
    const int soff = ((l & 7) ^ srow) * 8;  // shorts

    floatx4 zero = {0.f, 0.f, 0.f, 0.f};
    floatx4 acc[4][4];
#pragma unroll
    for (int r = 0; r < 4; ++r)
#pragma unroll
        for (int c = 0; c < 4; ++c) acc[r][c] = zero;

    for (int kk = 0; kk < KTOT; kk += BK) {
        const short* Asrc = A0 + (size_t)(kk >> 7) * ((size_t)NP * 128) + (kk & 127);
        const short* Bsrc = Wt + kk;
#pragma unroll
        for (int i = 0; i < 4; ++i) {
            int seg = w * 4 + i;            // 0..15
            int row = seg * 8 + srow;       // 0..127
            GLDS(Asrc + (size_t)(m0 + row) * D + soff, As + seg * 512);
            GLDS(Bsrc + (size_t)(n0 + row) * KTOT + soff, Bs + seg * 512);
        }
        __syncthreads();
#pragma unroll
        for (int j = 0; j < 2; ++j) {
            short8 af[4], bfr[4];
#pragma unroll
            for (int r = 0; r < 4; ++r) {
                int row = wr + r * 16 + lm;
                int ch = (lg + 4 * j) ^ (row & 7);
                af[r] = *(const short8*)&As[row * BK + ch * 8];
            }
#pragma unroll
            for (int c = 0; c < 4; ++c) {
                int row = wc + c * 16 + lm;
                int ch = (lg + 4 * j) ^ (row & 7);
                bfr[c] = *(const short8*)&Bs[row * BK + ch * 8];
            }
#pragma unroll
            for (int r = 0; r < 4; ++r)
#pragma unroll
                for (int c = 0; c < 4; ++c)
                    acc[r][c] = __builtin_amdgcn_mfma_f32_16x16x32_bf16(af[r], bfr[c],
                                                                        acc[r][c], 0, 0, 0);
        }
        __syncthreads();
    }

    const int q4 = lg * 4;
#pragma unroll
    for (int r = 0; r < 4; ++r) {
#pragma unroll
        for (int i = 0; i < 4; ++i) {
            int m = m0 + wr + r * 16 + q4 + i;
            if (m < NN) {
#pragma unroll
                for (int c = 0; c < 4; ++c) {
                    int n = n0 + wc + c * 16 + lm;
                    float v = acc[r][c][i] + bias[n];
                    C[(size_t)m * UNITS + n] = fmaxf(v, 0.f);
                }
            }
        }
    }
}

extern "C" void kernel_launch(void* const* d_in, const int* in_sizes, int n_in,
                              void* d_out, int out_size, void* d_ws, size_t ws_size,
                              hipStream_t stream) {
    const float* x = (const float*)d_in[0];
    const int* ei = (const int*)d_in[1];
    const float* ew_in = (const float*)d_in[2];
    const float* W = (const float*)d_in[3];
    const float* bias = (const float*)d_in[4];
    float* out = (float*)d_out;

    const int* row = ei;
    const int* col = ei + NE;

    // workspace layout (4-byte units)
    float* dis = (float*)d_ws;                  // NN
    int* cnt16 = (int*)(dis + NN);              // 16*NN
    int* rank = cnt16 + NREP * NN;              // NE
    int* bsum = rank + NE;                      // 64
    int* row_ptr = bsum + 64;                   // NN+2
    int2* edges = (int2*)(row_ptr + NN + 2);    // NE int2
    unsigned* xb = (unsigned*)(edges + NE) + 2; // +2 pads to 16 B alignment for uint4
    unsigned* h1b = xb + (size_t)NP * 64;
    unsigned* h2b = h1b + (size_t)NP * 64;
    unsigned* h3b = h2b + (size_t)NP * 64;
    short* Wt = (short*)(h3b + (size_t)NP * 64);  // 256*512 bf16

    hipMemsetAsync(cnt16, 0, NREP * NN * sizeof(int), stream);

    count_kernel<<<(NE + 255) / 256, 256, 0, stream>>>(row, cnt16, rank, NE);
    scanA_kernel<<<SCAN_NB, 256, 0, stream>>>(cnt16, row_ptr, bsum);
    scanB_kernel<<<1, 64, 0, stream>>>(bsum, row_ptr);
    scanC_kernel<<<SCAN_NB, 256, 0, stream>>>(row_ptr, bsum);
    fill_kernel<<<(NE + 255) / 256, 256, 0, stream>>>(row, col, ew_in, rank, row_ptr, cnt16,
                                                      edges, NE);
    degdis_kernel<<<(NN + 3) / 4, 256, 0, stream>>>(row_ptr, edges, dis);
    prep_kernel<<<CONV_NB + 128, 256, 0, stream>>>(x, xb, W, Wt);

    int gat_blocks = (NN + 3) / 4;
    gather_kernel<true><<<gat_blocks, 256, 0, stream>>>(xb, h1b, row_ptr, edges, dis);
    gather_kernel<false><<<gat_blocks, 256, 0, stream>>>(h1b, h2b, row_ptr, edges, dis);
    gather_kernel<false><<<gat_blocks, 256, 0, stream>>>(h2b, h3b, row_ptr, edges, dis);

    gemm_mfma<<<dim3(NP / 128, UNITS / 128), 256, 0, stream>>>(
        (const short*)xb, Wt, bias, out);
}

// Round 10
// 315.366 us; speedup vs baseline: 1.0324x; 1.0324x over previous
//
#include <hip/hip_runtime.h>

#define NN 50000
#define NP 50048   // rows padded to multiple of 128
#define NE 800000
#define D 128
#define UNITS 256
#define KTOT 512
#define SCAN_NB 50   // 50 blocks x 1024 elements covers 50000
#define NREP 16
#define CONV_NB 6250 // NN*D/4/256

typedef __attribute__((ext_vector_type(8))) short short8;
typedef __attribute__((ext_vector_type(4))) float floatx4;

__device__ inline unsigned short f2b(float f) {          // fp32 -> bf16 RNE
    unsigned u = __float_as_uint(f);
    return (unsigned short)((u + 0x7fff + ((u >> 16) & 1)) >> 16);
}
__device__ inline float2 bx2f(unsigned v) {              // packed bf16x2 -> float2
    float2 r;
    r.x = __uint_as_float(v << 16);
    r.y = __uint_as_float(v & 0xffff0000u);
    return r;
}

// ---------- count: 16 replicated histograms + per-edge rank ----------
__global__ void count_kernel(const int* __restrict__ row, int* __restrict__ cnt16,
                             int* __restrict__ rank, int E) {
    int e = blockIdx.x * blockDim.x + threadIdx.x;
    if (e < E) {
        int rep = (e >> 6) & (NREP - 1);        // whole wave -> same replica
        rank[e] = atomicAdd(&cnt16[rep * NN + row[e]], 1);
    }
}

// ---------- 3-phase exclusive scan; also prefixes the 16 replicas per node ----------
__global__ __launch_bounds__(256) void scanA_kernel(int* __restrict__ cnt16,
                                                    int* __restrict__ row_ptr,
                                                    int* __restrict__ bsum) {
    __shared__ int s[256];
    int b = blockIdx.x, t = threadIdx.x;
    int base = b * 1024 + t * 4;
    int v[4];
    int sum = 0;
#pragma unroll
    for (int i = 0; i < 4; ++i) {
        int idx = base + i;
        int tot = 0;
        if (idx < NN) {
            int c[NREP];
            int run = 0;
#pragma unroll
            for (int r = 0; r < NREP; ++r) c[r] = cnt16[r * NN + idx];
#pragma unroll
            for (int r = 0; r < NREP; ++r) {
                cnt16[r * NN + idx] = run;
                run += c[r];
            }
            tot = run;
        }
        v[i] = tot;
        sum += tot;
    }
    s[t] = sum;
    __syncthreads();
    for (int off = 1; off < 256; off <<= 1) {
        int add = (t >= off) ? s[t - off] : 0;
        __syncthreads();
        s[t] += add;
        __syncthreads();
    }
    int run = s[t] - sum;
#pragma unroll
    for (int i = 0; i < 4; ++i) {
        int idx = base + i;
        if (idx < NN) row_ptr[idx] = run;
        run += v[i];
    }
    if (t == 255) bsum[b] = s[255];
}

__global__ void scanB_kernel(int* __restrict__ bsum, int* __restrict__ row_ptr) {
    if (threadIdx.x == 0 && blockIdx.x == 0) {
        int run = 0;
        for (int i = 0; i < SCAN_NB; ++i) {
            int v = bsum[i];
            bsum[i] = run;
            run += v;
        }
        row_ptr[NN] = run;
    }
}

__global__ __launch_bounds__(256) void scanC_kernel(int* __restrict__ row_ptr,
                                                    const int* __restrict__ bsum) {
    int b = blockIdx.x, t = threadIdx.x;
    int off = bsum[b];
    int base = b * 1024 + t * 4;
#pragma unroll
    for (int i = 0; i < 4; ++i) {
        int idx = base + i;
        if (idx < NN) row_ptr[idx] += off;
    }
}

// ---------- CSR fill (no atomics): (col, raw weight) records ----------
__global__ void fill_kernel(const int* __restrict__ row, const int* __restrict__ col,
                            const float* __restrict__ w, const int* __restrict__ rank,
                            const int* __restrict__ row_ptr, const int* __restrict__ cnt16,
                            int2* __restrict__ edges, int E) {
    int e = blockIdx.x * blockDim.x + threadIdx.x;
    if (e >= E) return;
    int r = row[e];
    int rep = (e >> 6) & (NREP - 1);
    int pos = row_ptr[r] + cnt16[rep * NN + r] + rank[e];
    edges[pos] = make_int2(col[e], __float_as_int(w[e]));
}

// ---------- per-node degree -> dis (wave per node, coalesced) ----------
__global__ __launch_bounds__(256) void degdis_kernel(const int* __restrict__ row_ptr,
                                                     const int2* __restrict__ edges,
                                                     float* __restrict__ dis) {
    int node = blockIdx.x * 4 + (threadIdx.x >> 6);
    int l = threadIdx.x & 63;
    if (node >= NN) return;
    int beg = row_ptr[node], end = row_ptr[node + 1];
    float s = 0.f;
    for (int e = beg + l; e < end; e += 64) s += __int_as_float(edges[e].y);
#pragma unroll
    for (int off = 32; off; off >>= 1) s += __shfl_down(s, off);
    if (l == 0) dis[node] = s > 0.f ? rsqrtf(s) : 0.f;
}

// ---------- prep: fp32->bf16 convert of x  +  W[512][256] -> Wt[256][512] bf16 ----------
__global__ __launch_bounds__(256) void prep_kernel(const float* __restrict__ x,
                                                   unsigned* __restrict__ xb,
                                                   const float* __restrict__ W,
                                                   short* __restrict__ Wt) {
    __shared__ float tile[32][33];
    if (blockIdx.x < CONV_NB) {
        int t = blockIdx.x * 256 + threadIdx.x;
        float4 v = ((const float4*)x)[t];
        uint2 o;
        o.x = (unsigned)f2b(v.x) | ((unsigned)f2b(v.y) << 16);
        o.y = (unsigned)f2b(v.z) | ((unsigned)f2b(v.w) << 16);
        ((uint2*)xb)[t] = o;
    } else {
        int b = blockIdx.x - CONV_NB;           // 0..127
        int kb = (b & 15) * 32;
        int nb = (b >> 4) * 32;
        int tx = threadIdx.x & 31, ty = threadIdx.x >> 5;
        for (int i = 0; i < 32; i += 8)
            tile[ty + i][tx] = W[(size_t)(kb + ty + i) * UNITS + nb + tx];
        __syncthreads();
        for (int i = 0; i < 32; i += 8)
            Wt[(size_t)(nb + ty + i) * KTOT + kb + tx] = (short)f2b(tile[tx][ty + i]);
    }
}

// ---------- propagation: 4 edges per wave-load, software-pipelined edge meta ----------
__device__ inline void acc8(float* acc, uint4 v, float w) {
    float2 f0 = bx2f(v.x), f1 = bx2f(v.y), f2 = bx2f(v.z), f3 = bx2f(v.w);
    acc[0] = fmaf(w, f0.x, acc[0]); acc[1] = fmaf(w, f0.y, acc[1]);
    acc[2] = fmaf(w, f1.x, acc[2]); acc[3] = fmaf(w, f1.y, acc[3]);
    acc[4] = fmaf(w, f2.x, acc[4]); acc[5] = fmaf(w, f2.y, acc[5]);
    acc[6] = fmaf(w, f3.x, acc[6]); acc[7] = fmaf(w, f3.y, acc[7]);
}

template <bool NORM>
__global__ __launch_bounds__(256) void gather_kernel(const unsigned* __restrict__ hprev,
                                                     unsigned* __restrict__ hnext,
                                                     const int* __restrict__ row_ptr,
                                                     int2* __restrict__ edges,
                                                     const float* __restrict__ dis) {
    int node = blockIdx.x * 4 + (threadIdx.x >> 6);
    if (node >= NN) return;
    int l = threadIdx.x & 63;
    int g = l >> 4;           // edge subgroup 0..3
    int s = l & 15;           // feature segment
    const uint4* hp4 = (const uint4*)hprev;   // one row = 16 uint4
    int beg = row_ptr[node], end = row_ptr[node + 1];
    float dr = NORM ? dis[node] : 1.f;

    float acc[8] = {0.f, 0.f, 0.f, 0.f, 0.f, 0.f, 0.f, 0.f};
    // preload first batch's meta
    int2 M0 = edges[(beg + g) < end ? (beg + g) : end - 1];
    int2 M1 = edges[(beg + 4 + g) < end ? (beg + 4 + g) : end - 1];
    for (int e = beg; e < end; e += 8) {
        int i0 = e + g;
        int i1 = e + 4 + g;
        int2 E0 = M0, E1 = M1;
        int en = e + 8;
        if (en < end) {                        // wave-uniform prefetch of next meta
            int j0 = en + g, j1 = en + 4 + g;
            M0 = edges[j0 < end ? j0 : end - 1];
            M1 = edges[j1 < end ? j1 : end - 1];
        }
        float w0 = __int_as_float(E0.y);
        float w1 = __int_as_float(E1.y);
        if (NORM) {
            w0 *= dr * dis[E0.x];
            w1 *= dr * dis[E1.x];
        }
        w0 = (i0 < end) ? w0 : 0.f;
        w1 = (i1 < end) ? w1 : 0.f;
        uint4 v0 = hp4[(size_t)E0.x * 16 + s];
        uint4 v1 = hp4[(size_t)E1.x * 16 + s];
        acc8(acc, v0, w0);
        acc8(acc, v1, w1);
        if (NORM && s == 0) {                  // persist normalized weights for hops 2/3
            if (i0 < end) edges[i0].y = __float_as_int(w0);
            if (i1 < end) edges[i1].y = __float_as_int(w1);
        }
    }
    // butterfly over the 4 groups (lane bits 4,5)
#pragma unroll
    for (int i = 0; i < 8; ++i) {
        acc[i] += __shfl_xor(acc[i], 16);
        acc[i] += __shfl_xor(acc[i], 32);
    }
    if (g == 0) {
        uint4 sv = hp4[(size_t)node * 16 + s];   // self loop, weight 1
        acc8(acc, sv, 1.f);
        uint4 o;
        o.x = (unsigned)f2b(acc[0]) | ((unsigned)f2b(acc[1]) << 16);
        o.y = (unsigned)f2b(acc[2]) | ((unsigned)f2b(acc[3]) << 16);
        o.z = (unsigned)f2b(acc[4]) | ((unsigned)f2b(acc[5]) << 16);
        o.w = (unsigned)f2b(acc[6]) | ((unsigned)f2b(acc[7]) << 16);
        ((uint4*)hnext)[(size_t)node * 16 + s] = o;
    }
}

// ---------- MFMA GEMM: out[NP,256] = relu(bias + A[m][512] @ Wt^T) ----------
#define BK 64
#define GLDS(g, l)                                                                      \
    __builtin_amdgcn_global_load_lds((const __attribute__((address_space(1))) void*)(g), \
                                     (__attribute__((address_space(3))) void*)(l), 16, 0, 0)

__global__ __launch_bounds__(256) void gemm_mfma(const short* __restrict__ A0,
                                                 const short* __restrict__ Wt,
                                                 const float* __restrict__ bias,
                                                 float* __restrict__ C) {
    __shared__ short As[128 * BK];   // 16 KB, [m][k], chunk c stored at c^(row&7)
    __shared__ short Bs[128 * BK];   // 16 KB, [n][k]
    const int t = threadIdx.x;
    const int m0 = blockIdx.x * 128;
    const int n0 = blockIdx.y * 128;
    const int w = t >> 6;
    const int l = t & 63;
    const int wr = (w >> 1) * 64;
    const int wc = (w & 1) * 64;
    const int lm = l & 15;
    const int lg = l >> 4;                  // 0..3

    const int srow = l >> 3;                // 0..7
    const int soff = ((l & 7) ^ srow) * 8;  // shorts

    floatx4 zero = {0.f, 0.f, 0.f, 0.f};
    floatx4 acc[4][4];
#pragma unroll
    for (int r = 0; r < 4; ++r)
#pragma unroll
        for (int c = 0; c < 4; ++c) acc[r][c] = zero;

    for (int kk = 0; kk < KTOT; kk += BK) {
        const short* Asrc = A0 + (size_t)(kk >> 7) * ((size_t)NP * 128) + (kk & 127);
        const short* Bsrc = Wt + kk;
#pragma unroll
        for (int i = 0; i < 4; ++i) {
            int seg = w * 4 + i;            // 0..15
            int row = seg * 8 + srow;       // 0..127
            GLDS(Asrc + (size_t)(m0 + row) * D + soff, As + seg * 512);
            GLDS(Bsrc + (size_t)(n0 + row) * KTOT + soff, Bs + seg * 512);
        }
        __syncthreads();
#pragma unroll
        for (int j = 0; j < 2; ++j) {
            short8 af[4], bfr[4];
#pragma unroll
            for (int r = 0; r < 4; ++r) {
                int row = wr + r * 16 + lm;
                int ch = (lg + 4 * j) ^ (row & 7);
                af[r] = *(const short8*)&As[row * BK + ch * 8];
            }
#pragma unroll
            for (int c = 0; c < 4; ++c) {
                int row = wc + c * 16 + lm;
                int ch = (lg + 4 * j) ^ (row & 7);
                bfr[c] = *(const short8*)&Bs[row * BK + ch * 8];
            }
#pragma unroll
            for (int r = 0; r < 4; ++r)
#pragma unroll
                for (int c = 0; c < 4; ++c)
                    acc[r][c] = __builtin_amdgcn_mfma_f32_16x16x32_bf16(af[r], bfr[c],
                                                                        acc[r][c], 0, 0, 0);
        }
        __syncthreads();
    }

    const int q4 = lg * 4;
#pragma unroll
    for (int r = 0; r < 4; ++r) {
#pragma unroll
        for (int i = 0; i < 4; ++i) {
            int m = m0 + wr + r * 16 + q4 + i;
            if (m < NN) {
#pragma unroll
                for (int c = 0; c < 4; ++c) {
                    int n = n0 + wc + c * 16 + lm;
                    float v = acc[r][c][i] + bias[n];
                    C[(size_t)m * UNITS + n] = fmaxf(v, 0.f);
                }
            }
        }
    }
}

extern "C" void kernel_launch(void* const* d_in, const int* in_sizes, int n_in,
                              void* d_out, int out_size, void* d_ws, size_t ws_size,
                              hipStream_t stream) {
    const float* x = (const float*)d_in[0];
    const int* ei = (const int*)d_in[1];
    const float* ew_in = (const float*)d_in[2];
    const float* W = (const float*)d_in[3];
    const float* bias = (const float*)d_in[4];
    float* out = (float*)d_out;

    const int* row = ei;
    const int* col = ei + NE;

    // workspace layout (4-byte units)
    float* dis = (float*)d_ws;                  // NN
    int* cnt16 = (int*)(dis + NN);              // 16*NN
    int* rank = cnt16 + NREP * NN;              // NE
    int* bsum = rank + NE;                      // 64
    int* row_ptr = bsum + 64;                   // NN+2
    int2* edges = (int2*)(row_ptr + NN + 2);    // NE int2
    unsigned* xb = (unsigned*)(edges + NE) + 2; // +2 pads to 16 B alignment for uint4
    unsigned* h1b = xb + (size_t)NP * 64;
    unsigned* h2b = h1b + (size_t)NP * 64;
    unsigned* h3b = h2b + (size_t)NP * 64;
    short* Wt = (short*)(h3b + (size_t)NP * 64);  // 256*512 bf16

    hipMemsetAsync(cnt16, 0, NREP * NN * sizeof(int), stream);

    count_kernel<<<(NE + 255) / 256, 256, 0, stream>>>(row, cnt16, rank, NE);
    scanA_kernel<<<SCAN_NB, 256, 0, stream>>>(cnt16, row_ptr, bsum);
    scanB_kernel<<<1, 64, 0, stream>>>(bsum, row_ptr);
    scanC_kernel<<<SCAN_NB, 256, 0, stream>>>(row_ptr, bsum);
    fill_kernel<<<(NE + 255) / 256, 256, 0, stream>>>(row, col, ew_in, rank, row_ptr, cnt16,
                                                      edges, NE);
    degdis_kernel<<<(NN + 3) / 4, 256, 0, stream>>>(row_ptr, edges, dis);
    prep_kernel<<<CONV_NB + 128, 256, 0, stream>>>(x, xb, W, Wt);

    int gat_blocks = (NN + 3) / 4;
    gather_kernel<true><<<gat_blocks, 256, 0, stream>>>(xb, h1b, row_ptr, edges, dis);
    gather_kernel<false><<<gat_blocks, 256, 0, stream>>>(h1b, h2b, row_ptr, edges, dis);
    gather_kernel<false><<<gat_blocks, 256, 0, stream>>>(h2b, h3b, row_ptr, edges, dis);

    gemm_mfma<<<dim3(NP / 128, UNITS / 128), 256, 0, stream>>>(
        (const short*)xb, Wt, bias, out);
}